// Round 3
// baseline (516.819 us; speedup 1.0000x reference)
//
#include <hip/hip_runtime.h>
#include <stdint.h>

// topk(values+indices), x: (2,4096,50257) fp32, k=50, last axis, largest, sorted.
// d_out layout (flat float32): [rows*k values][rows*k indices-as-float]
//
// R3: phase-1 is a device-wide LINEAR grid-stride scan (fill-kernel address
// pattern: all resident waves sweep one contiguous window) with 4-deep
// explicit load batching (64 B/thread/iter, one fmax-tree branch per 16
// elements). Candidates (v > 2.75, ~150/row for N(0,1)) are appended to
// per-row global lists via atomicAdd. Phase-2 bitonic-sorts each row's
// candidates by (value desc, index asc) — lowest-index tie-break matches
// jax.lax.top_k. Rows whose count falls outside [k, cap] (never, for this
// data) are deterministically rescanned+bisected inside phase-2, ignoring
// the (drop-order-nondeterministic) ws content. Monolithic fallback if ws
// is too small or the input is misaligned.

#define TPB 256
#define SCAP 512   // candidate capacity per row (power of two)
#define MCAP 2048  // monolithic-fallback capacity
#define THR0 2.75f // ~150 expected hits/row of 50257 for N(0,1); 8-sigma > k=50

__device__ __forceinline__ unsigned ordf(float f) {
  unsigned s = __float_as_uint(f);
  return (s & 0x80000000u) ? ~s : (s | 0x80000000u);
}
__device__ __forceinline__ float unordf(unsigned u) {
  unsigned s = (u & 0x80000000u) ? (u ^ 0x80000000u) : ~u;
  return __uint_as_float(s);
}

// Bitonic sort over np2 (power of two) elements: descending by value,
// ascending index on ties.
__device__ __forceinline__ void bitonic_desc(float* cv, unsigned* ci, int np2, int tid) {
  for (int sz = 2; sz <= np2; sz <<= 1) {
    for (int st = sz >> 1; st > 0; st >>= 1) {
      for (int t = tid; t < (np2 >> 1); t += TPB) {
        int i = ((t & ~(st - 1)) << 1) | (t & (st - 1));
        int j = i | st;
        bool segDesc = ((i & sz) == 0);
        float va = cv[i], vb = cv[j];
        unsigned ia = ci[i], ib = ci[j];
        bool aFirst = (va > vb) || (va == vb && ia < ib);
        if (segDesc ? !aFirst : aFirst) {
          cv[i] = vb; cv[j] = va; ci[i] = ib; ci[j] = ia;
        }
      }
      __syncthreads();
    }
  }
}

// ---------------- counter zeroing ----------------
__global__ __launch_bounds__(TPB) void zero_cnt_kernel(int* __restrict__ wscnt, int rows) {
  int i = blockIdx.x * TPB + threadIdx.x;
  if (i < rows) wscnt[i] = 0;
}

// ---------------- Phase 1: linear streaming scan ----------------
__device__ __forceinline__ void emit_cand(float v, unsigned idx, unsigned V,
                                          float* __restrict__ wsv,
                                          unsigned* __restrict__ wsi,
                                          int* __restrict__ wscnt, int cap) {
  unsigned row = idx / V;            // rare path: ~0.3% of elements
  unsigned col = idx - row * V;
  int p = atomicAdd(&wscnt[row], 1);
  if (p < cap) {
    wsv[(size_t)row * cap + p] = v;
    wsi[(size_t)row * cap + p] = col;
  }
}

__device__ __forceinline__ void proc_grp(float4 v, size_t g, float thr, unsigned V,
                                         float* __restrict__ wsv,
                                         unsigned* __restrict__ wsi,
                                         int* __restrict__ wscnt, int cap) {
  float m = fmaxf(fmaxf(v.x, v.y), fmaxf(v.z, v.w));
  if (m > thr) {
    unsigned e = (unsigned)(g << 2);
    if (v.x > thr) emit_cand(v.x, e + 0u, V, wsv, wsi, wscnt, cap);
    if (v.y > thr) emit_cand(v.y, e + 1u, V, wsv, wsi, wscnt, cap);
    if (v.z > thr) emit_cand(v.z, e + 2u, V, wsv, wsi, wscnt, cap);
    if (v.w > thr) emit_cand(v.w, e + 3u, V, wsv, wsi, wscnt, cap);
  }
}

__global__ __launch_bounds__(TPB) void topk_scan_linear_kernel(
    const float4* __restrict__ xv, size_t ngroups, int V, float thr,
    float* __restrict__ wsv, unsigned* __restrict__ wsi,
    int* __restrict__ wscnt, int cap) {
  const size_t gid  = (size_t)blockIdx.x * TPB + threadIdx.x;
  const size_t nthr = (size_t)gridDim.x * TPB;
  const size_t step = nthr * 4;
  const unsigned Vu = (unsigned)V;

  size_t base = 0;
  for (; base + step <= ngroups; base += step) {
    size_t g0 = base + gid;
    float4 v0 = xv[g0];
    float4 v1 = xv[g0 + nthr];
    float4 v2 = xv[g0 + 2 * nthr];
    float4 v3 = xv[g0 + 3 * nthr];
    proc_grp(v0, g0,            thr, Vu, wsv, wsi, wscnt, cap);
    proc_grp(v1, g0 + nthr,     thr, Vu, wsv, wsi, wscnt, cap);
    proc_grp(v2, g0 + 2 * nthr, thr, Vu, wsv, wsi, wscnt, cap);
    proc_grp(v3, g0 + 3 * nthr, thr, Vu, wsv, wsi, wscnt, cap);
  }
  for (size_t g = base + gid; g < ngroups; g += nthr)
    proc_grp(xv[g], g, thr, Vu, wsv, wsi, wscnt, cap);
}

// ---------------- Phase 2: per-row sort (with deterministic fallback) ----------------
__global__ __launch_bounds__(TPB) void topk_sort_kernel(
    const float* __restrict__ x, const float* __restrict__ wsv,
    const unsigned* __restrict__ wsi, const int* __restrict__ wscnt,
    float* __restrict__ out, int rows, int V, int k, int cap, int out_half) {
  const int row = blockIdx.x;
  const int tid = threadIdx.x;

  __shared__ float cv[SCAP];
  __shared__ unsigned ci[SCAP];
  __shared__ int s_cnt;

  int cnt = wscnt[row];

  if (cnt >= k && cnt <= cap) {
    // Trusted: ws holds the complete set {v > thr} for this row.
    for (int t = tid; t < cnt; t += TPB) {
      cv[t] = wsv[(size_t)row * cap + t];
      ci[t] = wsi[(size_t)row * cap + t];
    }
  } else {
    // Fallback (pathological data only): deterministic rescan + bisect.
    const float* rp = x + (size_t)row * (size_t)V;
    unsigned lo = 0u, hi = 0xFFFFFFFFu;
    unsigned tu = ordf(THR0);
    cnt = 0;
    for (int attempt = 0; attempt < 48; ++attempt) {
      if (tid == 0) s_cnt = 0;
      __syncthreads();
      float thr = unordf(tu);
      for (int i = tid; i < V; i += TPB) {
        float v = rp[i];
        if (v > thr) {
          int p = atomicAdd(&s_cnt, 1);
          if (p < SCAP) { cv[p] = v; ci[p] = (unsigned)i; }
        }
      }
      __syncthreads();
      cnt = s_cnt;
      if (cnt >= k && cnt <= SCAP) break;
      if (hi <= lo + 1u) break;  // mass ties: accept
      if (cnt > SCAP) lo = tu; else hi = tu;
      unsigned mid = (unsigned)(((unsigned long long)lo + (unsigned long long)hi) >> 1);
      if (mid == tu) break;
      tu = mid;
      __syncthreads();
    }
    if (cnt > SCAP) cnt = SCAP;
  }

  int np2 = 64;
  while (np2 < cnt) np2 <<= 1;
  for (int t = cnt + tid; t < np2; t += TPB) { cv[t] = -INFINITY; ci[t] = 0xFFFFFFFFu; }
  __syncthreads();

  bitonic_desc(cv, ci, np2, tid);

  float* out_vals = out;
  float* out_idx  = out + out_half;
  for (int t = tid; t < k; t += TPB) {
    out_vals[(size_t)row * k + t] = cv[t];
    out_idx[(size_t)row * k + t]  = (float)ci[t];
  }
}

// ---------------- Fallback: monolithic (proven R1 kernel) ----------------
__global__ __launch_bounds__(TPB) void topk_mono_kernel(
    const float* __restrict__ x, float* __restrict__ out,
    int rows, int V, int k, int out_half) {
  const int row = blockIdx.x;
  const int tid = threadIdx.x;
  const float* rp = x + (size_t)row * (size_t)V;

  __shared__ float cv[MCAP];
  __shared__ unsigned ci[MCAP];
  __shared__ int s_cnt;

  unsigned mis = (unsigned)((size_t)rp & 15u);
  int head = (int)(((16u - mis) & 15u) >> 2);
  if (head > V) head = V;
  int nvec = (V - head) >> 2;
  int tail_start = head + nvec * 4;
  const float4* vp = (const float4*)(rp + head);

  unsigned lo = 0u, hi = 0xFFFFFFFFu;
  unsigned tu = ordf(2.5f);
  int cnt = 0;

  for (int attempt = 0; attempt < 48; ++attempt) {
    if (tid == 0) s_cnt = 0;
    __syncthreads();
    float thr = unordf(tu);
    for (int i = tid; i < head; i += TPB) {
      float v = rp[i];
      if (v > thr) { int p = atomicAdd(&s_cnt, 1); if (p < MCAP) { cv[p] = v; ci[p] = (unsigned)i; } }
    }
    for (int i = tail_start + tid; i < V; i += TPB) {
      float v = rp[i];
      if (v > thr) { int p = atomicAdd(&s_cnt, 1); if (p < MCAP) { cv[p] = v; ci[p] = (unsigned)i; } }
    }
    for (int j = tid; j < nvec; j += TPB) {
      float4 v = vp[j];
      int base = head + 4 * j;
      if (v.x > thr) { int p = atomicAdd(&s_cnt, 1); if (p < MCAP) { cv[p] = v.x; ci[p] = (unsigned)(base + 0); } }
      if (v.y > thr) { int p = atomicAdd(&s_cnt, 1); if (p < MCAP) { cv[p] = v.y; ci[p] = (unsigned)(base + 1); } }
      if (v.z > thr) { int p = atomicAdd(&s_cnt, 1); if (p < MCAP) { cv[p] = v.z; ci[p] = (unsigned)(base + 2); } }
      if (v.w > thr) { int p = atomicAdd(&s_cnt, 1); if (p < MCAP) { cv[p] = v.w; ci[p] = (unsigned)(base + 3); } }
    }
    __syncthreads();
    cnt = s_cnt;
    if (cnt >= k && cnt <= MCAP) break;
    if (hi <= lo + 1u) break;
    if (cnt > MCAP) lo = tu; else hi = tu;
    unsigned mid = (unsigned)(((unsigned long long)lo + (unsigned long long)hi) >> 1);
    if (mid == tu) break;
    tu = mid;
    __syncthreads();
  }
  if (cnt > MCAP) cnt = MCAP;

  int np2 = 64;
  while (np2 < cnt) np2 <<= 1;
  for (int i = cnt + tid; i < np2; i += TPB) { cv[i] = -INFINITY; ci[i] = 0xFFFFFFFFu; }
  __syncthreads();

  bitonic_desc(cv, ci, np2, tid);

  float* out_vals = out;
  float* out_idx  = out + out_half;
  for (int t = tid; t < k; t += TPB) {
    out_vals[(size_t)row * k + t] = cv[t];
    out_idx[(size_t)row * k + t]  = (float)ci[t];
  }
}

extern "C" void kernel_launch(void* const* d_in, const int* in_sizes, int n_in,
                              void* d_out, int out_size, void* d_ws, size_t ws_size,
                              hipStream_t stream) {
  const float* x = (const float*)d_in[0];
  const int k = 50;
  const int out_half = out_size / 2;  // rows * k
  const int rows = out_half / k;      // 8192
  const int V = in_sizes[0] / rows;   // 50257
  const size_t total = (size_t)in_sizes[0];

  // ws layout: [cnt: rows*4B][pad->256B][vals: rows*cap*4B][idx: rows*cap*4B]
  int cap = 0;
  size_t cnt_off = ((size_t)rows * 4 + 255) & ~(size_t)255;
  for (int c = SCAP; c >= 128; c >>= 1) {
    size_t need = cnt_off + (size_t)rows * (size_t)c * 8;
    if (need <= ws_size) { cap = c; break; }
  }
  bool aligned = (((size_t)x & 15u) == 0) && (total % 4 == 0);

  if (cap >= 128 && aligned) {
    char* ws = (char*)d_ws;
    int* wscnt = (int*)ws;
    float* wsv = (float*)(ws + cnt_off);
    unsigned* wsi = (unsigned*)(ws + cnt_off + (size_t)rows * (size_t)cap * 4);

    hipLaunchKernelGGL(zero_cnt_kernel, dim3((rows + TPB - 1) / TPB), dim3(TPB), 0, stream,
                       wscnt, rows);

    size_t ngroups = total >> 2;
    dim3 sgrid(2048), sblock(TPB);  // 8 blocks/CU resident, 0 LDS
    hipLaunchKernelGGL(topk_scan_linear_kernel, sgrid, sblock, 0, stream,
                       (const float4*)x, ngroups, V, THR0, wsv, wsi, wscnt, cap);

    hipLaunchKernelGGL(topk_sort_kernel, dim3(rows), dim3(TPB), 0, stream,
                       x, wsv, wsi, wscnt, (float*)d_out, rows, V, k, cap, out_half);
  } else {
    hipLaunchKernelGGL(topk_mono_kernel, dim3(rows), dim3(TPB), 0, stream,
                       x, (float*)d_out, rows, V, k, out_half);
  }
}

// Round 4
// 281.803 us; speedup vs baseline: 1.8340x; 1.8340x over previous
//
#include <hip/hip_runtime.h>
#include <stdint.h>

// topk(values+indices), x: (2,4096,50257) fp32, k=50, last axis, largest, sorted.
// d_out layout (flat float32): [rows*k values][rows*k indices-as-float]
//
// R4: back to the proven monolithic per-row kernel (R1 structure; R3's
// device-wide linear scan + global atomics regressed 325->516 us). One block
// per row streams the row once; elements > threshold go to an LDS candidate
// list; bisection on the ordered-uint threshold handles arbitrary data
// (never triggers for N(0,1)); LDS bitonic sort by (value desc, index asc)
// matches jax.lax.top_k tie-breaking.
//
// New this round (the lever): the main loop issues FOUR independent
// coalesced float4 loads per thread per iteration (32 outstanding
// loads/SIMD at 8 waves -- R1 had 8, just under the ~10 needed to cover
// ~900cy HBM latency at full BW), non-temporal (zero reuse), with one
// fmax-tree test per 64B (fuses to v_max3_f32).

#define TPB 256
#define MCAP 2048
#define THR0 2.75f  // ~150 expected hits/row of 50257 for N(0,1); 8-sigma above k=50

typedef float f32x4 __attribute__((ext_vector_type(4)));

__device__ __forceinline__ f32x4 ntld(const f32x4* p) {
  return __builtin_nontemporal_load(p);
}

__device__ __forceinline__ unsigned ordf(float f) {
  unsigned s = __float_as_uint(f);
  return (s & 0x80000000u) ? ~s : (s | 0x80000000u);
}
__device__ __forceinline__ float unordf(unsigned u) {
  unsigned s = (u & 0x80000000u) ? (u ^ 0x80000000u) : ~u;
  return __uint_as_float(s);
}

__device__ __forceinline__ float max4(f32x4 v) {
  return fmaxf(fmaxf(v[0], v[1]), fmaxf(v[2], v[3]));
}

__device__ __forceinline__ void emit4(f32x4 v, int base, float thr,
                                      float* cv, unsigned* ci, int* s_cnt) {
  #pragma unroll
  for (int e = 0; e < 4; ++e) {
    if (v[e] > thr) {
      int p = atomicAdd(s_cnt, 1);
      if (p < MCAP) { cv[p] = v[e]; ci[p] = (unsigned)(base + e); }
    }
  }
}

__global__ __launch_bounds__(TPB) void topk_mono_kernel(
    const float* __restrict__ x, float* __restrict__ out,
    int rows, int V, int k, int out_half) {
  const int row = blockIdx.x;
  const int tid = threadIdx.x;
  const float* rp = x + (size_t)row * (size_t)V;

  __shared__ float cv[MCAP];
  __shared__ unsigned ci[MCAP];
  __shared__ int s_cnt;

  // Per-row 16B alignment (V odd -> row bases cycle mod 16).
  unsigned mis = (unsigned)((size_t)rp & 15u);
  int head = (int)(((16u - mis) & 15u) >> 2);
  if (head > V) head = V;
  int nvec = (V - head) >> 2;
  int tail_start = head + nvec * 4;
  const f32x4* vp = (const f32x4*)(rp + head);
  int nvec4 = nvec & ~(4 * TPB - 1);  // multiple of 1024 groups (16KB/block/iter)

  unsigned lo = 0u, hi = 0xFFFFFFFFu;
  unsigned tu = ordf(THR0);
  int cnt = 0;

  for (int attempt = 0; attempt < 48; ++attempt) {
    if (tid == 0) s_cnt = 0;
    __syncthreads();
    float thr = unordf(tu);

    for (int i = tid; i < head; i += TPB) {
      float v = rp[i];
      if (v > thr) { int p = atomicAdd(&s_cnt, 1); if (p < MCAP) { cv[p] = v; ci[p] = (unsigned)i; } }
    }
    for (int i = tail_start + tid; i < V; i += TPB) {
      float v = rp[i];
      if (v > thr) { int p = atomicAdd(&s_cnt, 1); if (p < MCAP) { cv[p] = v; ci[p] = (unsigned)i; } }
    }

    // Main loop: 4 independent coalesced nt loads in flight per thread.
    for (int j0 = 0; j0 < nvec4; j0 += 4 * TPB) {
      int j = j0 + tid;
      f32x4 a = ntld(vp + j);
      f32x4 b = ntld(vp + j + TPB);
      f32x4 c = ntld(vp + j + 2 * TPB);
      f32x4 d = ntld(vp + j + 3 * TPB);
      float ma = max4(a), mb = max4(b), mc = max4(c), md = max4(d);
      if (fmaxf(fmaxf(ma, mb), fmaxf(mc, md)) > thr) {
        if (ma > thr) emit4(a, head + 4 * j,             thr, cv, ci, &s_cnt);
        if (mb > thr) emit4(b, head + 4 * (j + TPB),     thr, cv, ci, &s_cnt);
        if (mc > thr) emit4(c, head + 4 * (j + 2 * TPB), thr, cv, ci, &s_cnt);
        if (md > thr) emit4(d, head + 4 * (j + 3 * TPB), thr, cv, ci, &s_cnt);
      }
    }
    for (int j = nvec4 + tid; j < nvec; j += TPB) {
      f32x4 v = ntld(vp + j);
      if (max4(v) > thr) emit4(v, head + 4 * j, thr, cv, ci, &s_cnt);
    }

    __syncthreads();
    cnt = s_cnt;
    if (cnt >= k && cnt <= MCAP) break;
    if (hi <= lo + 1u) break;  // pathological mass-ties: accept
    if (cnt > MCAP) lo = tu; else hi = tu;
    unsigned mid = (unsigned)(((unsigned long long)lo + (unsigned long long)hi) >> 1);
    if (mid == tu) break;
    tu = mid;
    __syncthreads();
  }
  if (cnt > MCAP) cnt = MCAP;

  // Pad to power of two; bitonic sort (value desc, index asc).
  int np2 = 64;
  while (np2 < cnt) np2 <<= 1;
  for (int i = cnt + tid; i < np2; i += TPB) { cv[i] = -INFINITY; ci[i] = 0xFFFFFFFFu; }
  __syncthreads();

  for (int sz = 2; sz <= np2; sz <<= 1) {
    for (int st = sz >> 1; st > 0; st >>= 1) {
      for (int t = tid; t < (np2 >> 1); t += TPB) {
        int i = ((t & ~(st - 1)) << 1) | (t & (st - 1));
        int j = i | st;
        bool segDesc = ((i & sz) == 0);
        float va = cv[i], vb = cv[j];
        unsigned ia = ci[i], ib = ci[j];
        bool aFirst = (va > vb) || (va == vb && ia < ib);
        if (segDesc ? !aFirst : aFirst) {
          cv[i] = vb; cv[j] = va; ci[i] = ib; ci[j] = ia;
        }
      }
      __syncthreads();
    }
  }

  float* out_vals = out;
  float* out_idx  = out + out_half;
  for (int t = tid; t < k; t += TPB) {
    out_vals[(size_t)row * k + t] = cv[t];
    out_idx[(size_t)row * k + t]  = (float)ci[t];
  }
}

extern "C" void kernel_launch(void* const* d_in, const int* in_sizes, int n_in,
                              void* d_out, int out_size, void* d_ws, size_t ws_size,
                              hipStream_t stream) {
  const float* x = (const float*)d_in[0];
  const int k = 50;
  const int out_half = out_size / 2;  // rows * k
  const int rows = out_half / k;      // 8192
  const int V = in_sizes[0] / rows;   // 50257

  hipLaunchKernelGGL(topk_mono_kernel, dim3(rows), dim3(TPB), 0, stream,
                     x, (float*)d_out, rows, V, k, out_half);
}